// Round 3
// baseline (815.750 us; speedup 1.0000x reference)
//
#include <hip/hip_runtime.h>
#include <hip/hip_bf16.h>

// NewellGRUModel: B=512, S=1024, F=16, H=64.  bf16 in/out (proven r2..r13).
//
// r14: r13 post-mortem -- per-step wall 925 cyc, only ~342 issue: ~580 cyc of
// exposed serial latency (LDS h round-trip ~150, lgkm waits, ~60 trans tail)
// with 1 wave/SIMD. More waves can't help (recurrence is serial: batch time =
// 1024 x critical path). Fix: fill the stalls FROM INSIDE the wave -- each
// consumer wave interleaves TWO independent batches (lane l = unit l for A
// and B), sharing one copy of the packed f16 weights. A's LDS latency and
// trans tail hide under B's independent dot2 issue and vice versa. Producer
// wave serves both batches (8-step tiles, dbuf). Grid 256 x 128 thr; half
// the SIMDs idle by design (latency-bound, not issue-bound).

#define KEEP(x) asm volatile("" : "+v"(x))

typedef _Float16 f16x2 __attribute__((ext_vector_type(2)));
union H2U { unsigned int u; f16x2 h; };

#if defined(__has_builtin)
#  if __has_builtin(__builtin_amdgcn_fdot2)
#    define HAS_FDOT2 1
#  endif
#endif
#ifndef HAS_FDOT2
#  define HAS_FDOT2 0
#endif

// acc += h2[0]*w2[0] + h2[1]*w2[1]  (fp32 accumulate)
static __device__ __forceinline__ float dot2acc(unsigned int hraw, unsigned int wraw, float acc) {
    H2U a, b; a.u = hraw; b.u = wraw;
#if HAS_FDOT2
    return __builtin_amdgcn_fdot2(a.h, b.h, acc, false);
#else
    return fmaf((float)a.h.x, (float)b.h.x, fmaf((float)a.h.y, (float)b.h.y, acc));
#endif
}

template<bool BF16>
struct IO {
    static __device__ __forceinline__ float ld(const void* p, int i) {
        if constexpr (BF16) {
            unsigned short u = ((const unsigned short*)p)[i];
            union { unsigned int ui; float f; } c; c.ui = (unsigned int)u << 16;
            return c.f;
        } else {
            return ((const float*)p)[i];
        }
    }
    static __device__ __forceinline__ void st(void* p, int i, float v) {
        if constexpr (BF16) ((__hip_bfloat16*)p)[i] = __float2bfloat16(v);
        else ((float*)p)[i] = v;
    }
    // 4 consecutive elements, i % 4 == 0 (8B-aligned bf16 / 16B-aligned fp32)
    static __device__ __forceinline__ float4 ld4(const void* p, int i) {
        if constexpr (BF16) {
            const ushort4 u = ((const ushort4*)p)[i >> 2];
            union { unsigned int ui; float f; } a, b, c, d;
            a.ui = (unsigned int)u.x << 16; b.ui = (unsigned int)u.y << 16;
            c.ui = (unsigned int)u.z << 16; d.ui = (unsigned int)u.w << 16;
            return make_float4(a.f, b.f, c.f, d.f);
        } else {
            return ((const float4*)p)[i >> 2];
        }
    }
};

// mode: 0 = buffers are bf16, 1 = buffers are fp32.
__global__ void detect_dtype_kernel(const void* rkbuf, int* flag) {
    const float* f = (const float*)rkbuf;
    int ok = 0;
    for (int i = 0; i < 64; ++i) {
        float a = fabsf(f[i]);
        ok += (a > 1e-5f && a < 2.0f) ? 1 : 0;
    }
    *flag = (ok >= 48) ? 1 : 0;
}

template<bool BF16>
__global__ __launch_bounds__(128, 1)
void gru_pc2_kernel(const void* __restrict__ inp, const void* __restrict__ gk,
                    const void* __restrict__ rk,  const void* __restrict__ gb,
                    const void* __restrict__ w1,  const void* __restrict__ b1v,
                    const void* __restrict__ gam, const void* __restrict__ bet,
                    const void* __restrict__ muv, const void* __restrict__ vav,
                    const void* __restrict__ w2,  const void* __restrict__ bb2,
                    const void* __restrict__ Tp,  const int* __restrict__ mode,
                    void* __restrict__ out)
{
    const int want = BF16 ? 0 : 1;
    if (*mode != want) return;   // uniform branch, whole block exits

    const int b0  = blockIdx.x * 2;   // this block owns batches b0, b0+1
    const int tid = threadIdx.x;      // 0..127
    const int w   = tid >> 6;         // wave 0 = consumer, wave 1 = producer
    const int l   = tid & 63;         // lane = output unit o

    // xp[buf][batch][step][unit][{z,r,xh,pad}] -- 8-step tiles, 32 KB
    __shared__ __align__(16) float xp[2][2][8][64][4];
    __shared__ __align__(16) float xs[2][8][16];     // raw x tiles (producer)
    __shared__ __align__(16) _Float16 hsf[2][64];    // h broadcast, packed f16
    __shared__ __align__(16) float sred[2][64];      // epilogue states
    __shared__ float dsh[2];                         // delta-channel sums

    using io = IO<BF16>;

    if (w == 1) {
        // ================= PRODUCER (both batches) =================
        float kz[15], kr[15], kh[15];
#pragma unroll
        for (int c = 0; c < 15; ++c) {
            kz[c] = io::ld(gk, c*192 + l);
            kr[c] = io::ld(gk, c*192 + 64 + l);
            kh[c] = io::ld(gk, c*192 + 128 + l);
            KEEP(kz[c]); KEEP(kr[c]); KEEP(kh[c]);
        }
        const float bz  = io::ld(gb, l)      + io::ld(gb, 192 + l);
        const float br  = io::ld(gb, 64 + l) + io::ld(gb, 192 + 64 + l);
        const float bax = io::ld(gb, 128 + l);
        float dsum0 = 0.0f, dsum1 = 0.0f;

        const int bat = l >> 5;       // staging role: 0..1
        const int q   = l & 31;       // 0..31 -> 4 elems of the 128-elem tile

        auto stage = [&](int t) {     // load x tile t for both batches
            float4 v = io::ld4(inp, (b0 + bat)*16384 + t*128 + q*4);
            *(float4*)&xs[bat][q >> 2][(q & 3) * 4] = v;   // same-wave DS
        };
        auto produce = [&](int buf) {
#pragma unroll 1
            for (int ab = 0; ab < 2; ++ab) {
#pragma unroll 1
                for (int s2 = 0; s2 < 8; ++s2) {
                    const float4* xr = (const float4*)&xs[ab][s2][0];  // uniform
                    const float4 x0 = xr[0], x1 = xr[1], x2 = xr[2], x3 = xr[3];
                    const float xc[16] = {x0.x,x0.y,x0.z,x0.w, x1.x,x1.y,x1.z,x1.w,
                                          x2.x,x2.y,x2.z,x2.w, x3.x,x3.y,x3.z,x3.w};
                    float az = bz, ar = br, ax = bax;
#pragma unroll
                    for (int c = 0; c < 15; ++c) {
                        az = fmaf(xc[c], kz[c], az);
                        ar = fmaf(xc[c], kr[c], ar);
                        ax = fmaf(xc[c], kh[c], ax);
                    }
                    if (ab == 0) dsum0 += xc[15]; else dsum1 += xc[15];
                    *(float4*)&xp[buf][ab][s2][l][0] = make_float4(az, ar, ax, 0.0f);
                }
            }
        };

        stage(0); produce(0);
        __syncthreads();                 // B0: tile 0 ready

#pragma unroll 1
        for (int t = 0; t < 128; ++t) {
            if (t < 127) {
                stage(t + 1);
                produce((t + 1) & 1);    // stays 1 tile ahead of consumer
            } else if (l == 0) {
                dsh[0] = dsum0; dsh[1] = dsum1;   // lane-uniform sums
            }
            __syncthreads();             // B(t+1)
        }
        return;
    }

    // ================= CONSUMER (batches A and B interleaved) =================
    // Recurrent weights packed f16x2 (shared by both batches): 96 dwords.
    unsigned int wzp[32], wrp[32], whp[32];
#pragma unroll
    for (int p = 0; p < 32; ++p) {
        H2U z, r, hh;
        z.h  = f16x2{(_Float16)io::ld(rk, (2*p)*192 + l),
                     (_Float16)io::ld(rk, (2*p+1)*192 + l)};
        r.h  = f16x2{(_Float16)io::ld(rk, (2*p)*192 + 64 + l),
                     (_Float16)io::ld(rk, (2*p+1)*192 + 64 + l)};
        hh.h = f16x2{(_Float16)io::ld(rk, (2*p)*192 + 128 + l),
                     (_Float16)io::ld(rk, (2*p+1)*192 + 128 + l)};
        wzp[p] = z.u; wrp[p] = r.u; whp[p] = hh.u;
        KEEP(wzp[p]); KEEP(wrp[p]); KEEP(whp[p]);
    }
    const float bah = io::ld(gb, 192 + 128 + l);   // b_r[h]

    uint4 ha[8], hb[8];
#pragma unroll
    for (int i = 0; i < 8; ++i) { ha[i] = make_uint4(0,0,0,0); hb[i] = make_uint4(0,0,0,0); }
    float hA = 0.0f, hB = 0.0f;

    // one GRU step for one batch: dots from hr regs, gates, write h, reload hr
    auto step_batch = [&](uint4 (&hr)[8], const float4& xpv, float& h,
                          _Float16* hbuf) {
        float az = xpv.x, ar = xpv.y;
        const float ax = xpv.z;
        float ah = bah;
        float az1 = 0.0f, ar1 = 0.0f, ah1 = 0.0f;
#pragma unroll
        for (int i = 0; i < 4; ++i) {
            const uint4 d = hr[i];
            az = dot2acc(d.x, wzp[4*i+0], az); ar = dot2acc(d.x, wrp[4*i+0], ar); ah = dot2acc(d.x, whp[4*i+0], ah);
            az = dot2acc(d.y, wzp[4*i+1], az); ar = dot2acc(d.y, wrp[4*i+1], ar); ah = dot2acc(d.y, whp[4*i+1], ah);
            az = dot2acc(d.z, wzp[4*i+2], az); ar = dot2acc(d.z, wrp[4*i+2], ar); ah = dot2acc(d.z, whp[4*i+2], ah);
            az = dot2acc(d.w, wzp[4*i+3], az); ar = dot2acc(d.w, wrp[4*i+3], ar); ah = dot2acc(d.w, whp[4*i+3], ah);
        }
#pragma unroll
        for (int i = 4; i < 8; ++i) {
            const uint4 d = hr[i];
            az1 = dot2acc(d.x, wzp[4*i+0], az1); ar1 = dot2acc(d.x, wrp[4*i+0], ar1); ah1 = dot2acc(d.x, whp[4*i+0], ah1);
            az1 = dot2acc(d.y, wzp[4*i+1], az1); ar1 = dot2acc(d.y, wrp[4*i+1], ar1); ah1 = dot2acc(d.y, whp[4*i+1], ah1);
            az1 = dot2acc(d.z, wzp[4*i+2], az1); ar1 = dot2acc(d.z, wrp[4*i+2], ar1); ah1 = dot2acc(d.z, whp[4*i+2], ah1);
            az1 = dot2acc(d.w, wzp[4*i+3], az1); ar1 = dot2acc(d.w, wrp[4*i+3], ar1); ah1 = dot2acc(d.w, whp[4*i+3], ah1);
        }
        az += az1; ar += ar1; ah += ah1;

        const float z   = __builtin_amdgcn_rcpf(1.0f + __expf(-az));
        const float r   = __builtin_amdgcn_rcpf(1.0f + __expf(-ar));
        const float pre = fmaf(r, ah, ax);
        const float e2  = __expf(2.0f * pre);
        const float th  = 1.0f - 2.0f * __builtin_amdgcn_rcpf(e2 + 1.0f);
        h = fmaf(z, h - th, th);     // z*h + (1-z)*tanh

        hbuf[l] = (_Float16)h;       // same-wave DS pipe: in-order
        const uint4* hp = (const uint4*)hbuf;   // uniform addr, broadcast
#pragma unroll
        for (int i = 0; i < 8; ++i) hr[i] = hp[i];   // reads in flight; next
    };                                               // use waits only on these

    __syncthreads();                 // B0: tile 0 ready
    float4 xA = *(const float4*)&xp[0][0][0][l][0];
    float4 xB = *(const float4*)&xp[0][1][0][l][0];

#pragma unroll 1
    for (int t = 0; t < 128; ++t) {
#pragma unroll 1
        for (int s2 = 0; s2 < 8; ++s2) {
            step_batch(ha, xA, hA, &hsf[0][0]);   // A latency hides under B
            if (s2 < 7) xA = *(const float4*)&xp[t & 1][0][s2 + 1][l][0];
            step_batch(hb, xB, hB, &hsf[1][0]);   // B latency hides under A
            if (s2 < 7) xB = *(const float4*)&xp[t & 1][1][s2 + 1][l][0];
        }
        __syncthreads();             // tile t consumed / tile t+1 ready
        if (t < 127) {
            xA = *(const float4*)&xp[(t + 1) & 1][0][0][l][0];
            xB = *(const float4*)&xp[(t + 1) & 1][1][0][l][0];
        }
    }

    // ---- epilogue: delta effect + dense head, both batches ----
    const float T0 = io::ld(Tp, 0);
    sred[0][l] = fmaf(T0 * (1.0f / 1024.0f), dsh[0], hA);
    sred[1][l] = fmaf(T0 * (1.0f / 1024.0f), dsh[1], hB);   // same-wave DS

    const int j = l;   // 0..63
    float accA = io::ld(b1v, j), accB = accA;
#pragma unroll
    for (int k = 0; k < 64; ++k) {
        const float wv = io::ld(w1, k*64 + j);
        accA = fmaf(sred[0][k], wv, accA);
        accB = fmaf(sred[1][k], wv, accB);
    }
    const float inv = rsqrtf(io::ld(vav, j) + 0.001f);       // BN_EPS
    const float mu = io::ld(muv, j), ga = io::ld(gam, j), be = io::ld(bet, j);
    accA = fmaf((fmaxf(accA, 0.0f) - mu) * inv, ga, be);
    accB = fmaf((fmaxf(accB, 0.0f) - mu) * inv, ga, be);

    const float w2j = io::ld(w2, j);
    float vA = accA * w2j, vB = accB * w2j;
#pragma unroll
    for (int off = 32; off > 0; off >>= 1) {
        vA += __shfl_down(vA, off);
        vB += __shfl_down(vB, off);
    }
    if (j == 0) {
        const float b2v = io::ld(bb2, 0);
        io::st(out, b0,     vA + b2v);
        io::st(out, b0 + 1, vB + b2v);
    }
}

extern "C" void kernel_launch(void* const* d_in, const int* in_sizes, int n_in,
                              void* d_out, int out_size, void* d_ws, size_t ws_size,
                              hipStream_t stream)
{
    const void* inp = d_in[0];   // (512,1024,16)
    const void* gk  = d_in[1];   // (15,192)
    const void* rk  = d_in[2];   // (64,192)
    const void* gb  = d_in[3];   // (2,192)
    const void* w1  = d_in[4];   // (64,64)
    const void* b1v = d_in[5];   // (64,)
    const void* gam = d_in[6];
    const void* bet = d_in[7];
    const void* muv = d_in[8];
    const void* vav = d_in[9];
    const void* w2  = d_in[10];  // (64,1)
    const void* bb2 = d_in[11];  // (1,)
    const void* Tp  = d_in[12];  // (1,)

    int* flag = (int*)d_ws;
    detect_dtype_kernel<<<dim3(1), dim3(1), 0, stream>>>(rk, flag);
    gru_pc2_kernel<true ><<<dim3(256), dim3(128), 0, stream>>>(
        inp, gk, rk, gb, w1, b1v, gam, bet, muv, vav, w2, bb2, Tp, flag, d_out);
    gru_pc2_kernel<false><<<dim3(256), dim3(128), 0, stream>>>(
        inp, gk, rk, gb, w1, b1v, gam, bet, muv, vav, w2, bb2, Tp, flag, d_out);
}

// Round 4
// 554.536 us; speedup vs baseline: 1.4710x; 1.4710x over previous
//
#include <hip/hip_runtime.h>
#include <hip/hip_bf16.h>

// NewellGRUModel: B=512, S=1024, F=16, H=64.  bf16 in/out (proven r2..r14).
//
// r15: r14 post-mortem -- interleaving 2 batches doubled live registers
// (2x32 h-state + 96 weights), AGPR parking got worse, step-pair wall = 2x
// single-step: zero overlap gained. Revert to single-batch wave; attack the
// ~465 cyc of exposed latency in r13 instead: (a) xpv LDS read was issued at
// top of iter and used immediately (~130 cyc exposed); (b) h round-trip
// (~140 cyc) had nothing independent to issue under it; (c) producer wave +
// barrier every 16 steps. Fix: ONE wave does everything. Raw x for the whole
// batch staged in 32 KB LDS once (fp32: two 32 KB halves, one restage at
// s=512). Per step: x-proj (45 f32 FMA, independent of h -- issues UNDER the
// h-read latency), prefetch next x raw (lands during dots+gates), h-dots
// (96 dot2), gates, h write + h-read issue. No barriers, no producer, no
// second wave. FP op order identical to r13 => absmax unchanged.

#define KEEP(x) asm volatile("" : "+v"(x))

typedef _Float16 f16x2 __attribute__((ext_vector_type(2)));
union H2U { unsigned int u; f16x2 h; };
union FU  { unsigned int u; float f; };

#if defined(__has_builtin)
#  if __has_builtin(__builtin_amdgcn_fdot2)
#    define HAS_FDOT2 1
#  endif
#endif
#ifndef HAS_FDOT2
#  define HAS_FDOT2 0
#endif

// acc += h2[0]*w2[0] + h2[1]*w2[1]  (fp32 accumulate)
static __device__ __forceinline__ float dot2acc(unsigned int hraw, unsigned int wraw, float acc) {
    H2U a, b; a.u = hraw; b.u = wraw;
#if HAS_FDOT2
    return __builtin_amdgcn_fdot2(a.h, b.h, acc, false);
#else
    return fmaf((float)a.h.x, (float)b.h.x, fmaf((float)a.h.y, (float)b.h.y, acc));
#endif
}

template<bool BF16>
struct IO {
    static __device__ __forceinline__ float ld(const void* p, int i) {
        if constexpr (BF16) {
            unsigned short u = ((const unsigned short*)p)[i];
            FU c; c.u = (unsigned int)u << 16;
            return c.f;
        } else {
            return ((const float*)p)[i];
        }
    }
    static __device__ __forceinline__ void st(void* p, int i, float v) {
        if constexpr (BF16) ((__hip_bfloat16*)p)[i] = __float2bfloat16(v);
        else ((float*)p)[i] = v;
    }
};

// mode: 0 = buffers are bf16, 1 = buffers are fp32.
__global__ void detect_dtype_kernel(const void* rkbuf, int* flag) {
    const float* f = (const float*)rkbuf;
    int ok = 0;
    for (int i = 0; i < 64; ++i) {
        float a = fabsf(f[i]);
        ok += (a > 1e-5f && a < 2.0f) ? 1 : 0;
    }
    *flag = (ok >= 48) ? 1 : 0;
}

template<bool BF16>
__global__ __launch_bounds__(64, 1)
void gru_sw_kernel(const void* __restrict__ inp, const void* __restrict__ gk,
                   const void* __restrict__ rk,  const void* __restrict__ gb,
                   const void* __restrict__ w1,  const void* __restrict__ b1v,
                   const void* __restrict__ gam, const void* __restrict__ bet,
                   const void* __restrict__ muv, const void* __restrict__ vav,
                   const void* __restrict__ w2,  const void* __restrict__ bb2,
                   const void* __restrict__ Tp,  const int* __restrict__ mode,
                   void* __restrict__ out)
{
    const int want = BF16 ? 0 : 1;
    if (*mode != want) return;   // uniform branch, whole block exits

    const int b = blockIdx.x;
    const int l = threadIdx.x;   // 0..63, lane = output unit

    // Raw x: BF16 -> whole batch (1024x16 bf16 = 32 KB); FP32 -> half batch
    // (512x16 f32 = 32 KB), restaged once at s=512.
    __shared__ __align__(16) unsigned char xsm[32768];
    __shared__ __align__(16) _Float16 hsf[64];
    __shared__ __align__(16) float sredf[64];

    using io = IO<BF16>;
    const uint4* gin = (const uint4*)inp;
    uint4* xv = (uint4*)xsm;

    // ---- stage x (single wave: DS in-order, no barrier ever) ----
    if constexpr (BF16) {
#pragma unroll 4
        for (int i = 0; i < 32; ++i)
            xv[i*64 + l] = gin[b*2048 + i*64 + l];      // whole batch, raw bf16
    } else {
#pragma unroll 4
        for (int i = 0; i < 32; ++i)
            xv[i*64 + l] = gin[b*4096 + i*64 + l];      // first half, raw f32
    }

    // ---- recurrent weights packed f16x2 (96 dwords; bf16->f16 exact) ----
    unsigned int wzp[32], wrp[32], whp[32];
#pragma unroll
    for (int p = 0; p < 32; ++p) {
        H2U z, r, hh;
        z.h  = f16x2{(_Float16)io::ld(rk, (2*p)*192 + l),
                     (_Float16)io::ld(rk, (2*p+1)*192 + l)};
        r.h  = f16x2{(_Float16)io::ld(rk, (2*p)*192 + 64 + l),
                     (_Float16)io::ld(rk, (2*p+1)*192 + 64 + l)};
        hh.h = f16x2{(_Float16)io::ld(rk, (2*p)*192 + 128 + l),
                     (_Float16)io::ld(rk, (2*p+1)*192 + 128 + l)};
        wzp[p] = z.u; wrp[p] = r.u; whp[p] = hh.u;
        KEEP(wzp[p]); KEEP(wrp[p]); KEEP(whp[p]);
    }
    // ---- x-proj weights, f32 (keeps r13's exact x-proj arithmetic) ----
    float kzf[15], krf[15], khf[15];
#pragma unroll
    for (int c = 0; c < 15; ++c) {
        kzf[c] = io::ld(gk, c*192 + l);
        krf[c] = io::ld(gk, c*192 + 64 + l);
        khf[c] = io::ld(gk, c*192 + 128 + l);
        KEEP(kzf[c]); KEEP(krf[c]); KEEP(khf[c]);
    }
    const float bz  = io::ld(gb, l)      + io::ld(gb, 192 + l);
    const float br  = io::ld(gb, 64 + l) + io::ld(gb, 192 + 64 + l);
    const float bax = io::ld(gb, 128 + l);
    const float bah = io::ld(gb, 192 + 128 + l);   // b_r[h]

    // ---- delta-channel partial sum over staged portion ----
    float dsum = 0.0f;
    if constexpr (BF16) {
        const unsigned short* xs16 = (const unsigned short*)xsm;
#pragma unroll
        for (int k = 0; k < 16; ++k) {
            FU c; c.u = (unsigned int)xs16[(l + 64*k)*16 + 15] << 16;
            dsum += c.f;
        }
    } else {
        const float* xsf = (const float*)xsm;
#pragma unroll
        for (int k = 0; k < 8; ++k)
            dsum += xsf[(l + 64*k)*16 + 15];
    }

    // ---- main loop ----
    uint4 hr[8];
#pragma unroll
    for (int i = 0; i < 8; ++i) hr[i] = make_uint4(0, 0, 0, 0);
    float h = 0.0f;

    // current/prefetch raw x regs (BF16: 8 dwords; FP32: 16 floats)
    uint4  cr16[2] = {}, pr16[2] = {};
    float4 cr32[4] = {}, pr32[4] = {};
    if constexpr (BF16) { cr16[0] = xv[0]; cr16[1] = xv[1]; }
    else { const float4* lp = (const float4*)xsm;
           cr32[0]=lp[0]; cr32[1]=lp[1]; cr32[2]=lp[2]; cr32[3]=lp[3]; }

#pragma unroll 1
    for (int s = 0; s < 1024; ++s) {
        if constexpr (!BF16) {
            if (s == 512) {   // restage second half + its delta partials
#pragma unroll 4
                for (int i = 0; i < 32; ++i)
                    xv[i*64 + l] = gin[b*4096 + 2048 + i*64 + l];
                const float* xsf = (const float*)xsm;
#pragma unroll
                for (int k = 0; k < 8; ++k)
                    dsum += xsf[(l + 64*k)*16 + 15];
                const float4* lp = (const float4*)xsm;
                cr32[0]=lp[0]; cr32[1]=lp[1]; cr32[2]=lp[2]; cr32[3]=lp[3];
            }
        }

        // unpack current x (data long since landed) + x-proj: 45 f32 FMA.
        // Independent of h -> issues under the previous step's h-read latency.
        float xc[16];
        if constexpr (BF16) {
            const unsigned int dw[8] = {cr16[0].x, cr16[0].y, cr16[0].z, cr16[0].w,
                                        cr16[1].x, cr16[1].y, cr16[1].z, cr16[1].w};
#pragma unroll
            for (int j = 0; j < 8; ++j) {
                FU lo, hi; lo.u = dw[j] << 16; hi.u = dw[j] & 0xffff0000u;
                xc[2*j] = lo.f; xc[2*j+1] = hi.f;
            }
        } else {
            xc[0]=cr32[0].x; xc[1]=cr32[0].y; xc[2]=cr32[0].z; xc[3]=cr32[0].w;
            xc[4]=cr32[1].x; xc[5]=cr32[1].y; xc[6]=cr32[1].z; xc[7]=cr32[1].w;
            xc[8]=cr32[2].x; xc[9]=cr32[2].y; xc[10]=cr32[2].z; xc[11]=cr32[2].w;
            xc[12]=cr32[3].x; xc[13]=cr32[3].y; xc[14]=cr32[3].z; xc[15]=cr32[3].w;
        }
        float az = bz, ar_ = br, ax = bax;
#pragma unroll
        for (int c = 0; c < 15; ++c) {         // same FP order as r13 producer
            az  = fmaf(xc[c], kzf[c], az);
            ar_ = fmaf(xc[c], krf[c], ar_);
            ax  = fmaf(xc[c], khf[c], ax);
        }

        // prefetch next step's raw x (lands during dots+gates; issued BEFORE
        // the h write/reads so the in-order DS queue returns it first)
        const bool pf = (s < 1023) && (BF16 || s != 511);
        if (pf) {
            if constexpr (BF16) {
                pr16[0] = xv[(s+1)*2]; pr16[1] = xv[(s+1)*2 + 1];
            } else {
                const float4* lp = (const float4*)xsm;
                pr32[0] = lp[((s+1)&511)*4];     pr32[1] = lp[((s+1)&511)*4+1];
                pr32[2] = lp[((s+1)&511)*4+2];   pr32[3] = lp[((s+1)&511)*4+3];
            }
        }

        // ---- h-dots: 96 dot2, two chains (exact r13 order) ----
        float ah = bah;
        float az1 = 0.0f, ar1 = 0.0f, ah1 = 0.0f;
#pragma unroll
        for (int i = 0; i < 4; ++i) {
            const uint4 d = hr[i];
            az  = dot2acc(d.x, wzp[4*i+0], az);  ar_ = dot2acc(d.x, wrp[4*i+0], ar_); ah  = dot2acc(d.x, whp[4*i+0], ah);
            az  = dot2acc(d.y, wzp[4*i+1], az);  ar_ = dot2acc(d.y, wrp[4*i+1], ar_); ah  = dot2acc(d.y, whp[4*i+1], ah);
            az  = dot2acc(d.z, wzp[4*i+2], az);  ar_ = dot2acc(d.z, wrp[4*i+2], ar_); ah  = dot2acc(d.z, whp[4*i+2], ah);
            az  = dot2acc(d.w, wzp[4*i+3], az);  ar_ = dot2acc(d.w, wrp[4*i+3], ar_); ah  = dot2acc(d.w, whp[4*i+3], ah);
        }
#pragma unroll
        for (int i = 4; i < 8; ++i) {
            const uint4 d = hr[i];
            az1 = dot2acc(d.x, wzp[4*i+0], az1); ar1 = dot2acc(d.x, wrp[4*i+0], ar1); ah1 = dot2acc(d.x, whp[4*i+0], ah1);
            az1 = dot2acc(d.y, wzp[4*i+1], az1); ar1 = dot2acc(d.y, wrp[4*i+1], ar1); ah1 = dot2acc(d.y, whp[4*i+1], ah1);
            az1 = dot2acc(d.z, wzp[4*i+2], az1); ar1 = dot2acc(d.z, wrp[4*i+2], ar1); ah1 = dot2acc(d.z, whp[4*i+2], ah1);
            az1 = dot2acc(d.w, wzp[4*i+3], az1); ar1 = dot2acc(d.w, wrp[4*i+3], ar1); ah1 = dot2acc(d.w, whp[4*i+3], ah1);
        }
        az += az1; ar_ += ar1; ah += ah1;

        const float z   = __builtin_amdgcn_rcpf(1.0f + __expf(-az));
        const float r   = __builtin_amdgcn_rcpf(1.0f + __expf(-ar_));
        const float pre = fmaf(r, ah, ax);
        const float e2  = __expf(2.0f * pre);
        const float th  = 1.0f - 2.0f * __builtin_amdgcn_rcpf(e2 + 1.0f);
        h = fmaf(z, h - th, th);     // z*h + (1-z)*tanh

        hsf[l] = (_Float16)h;        // same-wave DS: in-order
        const uint4* hp = (const uint4*)hsf;   // uniform addr, broadcast reads
#pragma unroll
        for (int i = 0; i < 8; ++i) hr[i] = hp[i];   // loads into hr; the lgkm
                                                     // wait lands at next dots,
                                                     // hidden by x-proj above
        if constexpr (BF16) { cr16[0] = pr16[0]; cr16[1] = pr16[1]; }
        else { cr32[0]=pr32[0]; cr32[1]=pr32[1]; cr32[2]=pr32[2]; cr32[3]=pr32[3]; }
    }

    // ---- epilogue: delta effect + dense head (single wave) ----
#pragma unroll
    for (int off = 1; off < 64; off <<= 1)
        dsum += __shfl_xor(dsum, off, 64);           // all lanes hold total
    const float T0 = io::ld(Tp, 0);
    const float state = fmaf(T0 * (1.0f / 1024.0f), dsum, h);
    sredf[l] = state;                                // same-wave DS, in-order

    const int j = l;   // 0..63
    float acc = io::ld(b1v, j);
#pragma unroll
    for (int k = 0; k < 64; ++k)
        acc = fmaf(sredf[k], io::ld(w1, k*64 + j), acc);
    acc = fmaxf(acc, 0.0f);                                  // ReLU
    const float inv = rsqrtf(io::ld(vav, j) + 0.001f);       // BN_EPS
    acc = fmaf((acc - io::ld(muv, j)) * inv, io::ld(gam, j), io::ld(bet, j));

    float v = acc * io::ld(w2, j);
#pragma unroll
    for (int off = 32; off > 0; off >>= 1)
        v += __shfl_down(v, off);
    if (j == 0) io::st(out, b, v + io::ld(bb2, 0));
}

extern "C" void kernel_launch(void* const* d_in, const int* in_sizes, int n_in,
                              void* d_out, int out_size, void* d_ws, size_t ws_size,
                              hipStream_t stream)
{
    const void* inp = d_in[0];   // (512,1024,16)
    const void* gk  = d_in[1];   // (15,192)
    const void* rk  = d_in[2];   // (64,192)
    const void* gb  = d_in[3];   // (2,192)
    const void* w1  = d_in[4];   // (64,64)
    const void* b1v = d_in[5];   // (64,)
    const void* gam = d_in[6];
    const void* bet = d_in[7];
    const void* muv = d_in[8];
    const void* vav = d_in[9];
    const void* w2  = d_in[10];  // (64,1)
    const void* bb2 = d_in[11];  // (1,)
    const void* Tp  = d_in[12];  // (1,)

    int* flag = (int*)d_ws;
    detect_dtype_kernel<<<dim3(1), dim3(1), 0, stream>>>(rk, flag);
    gru_sw_kernel<true ><<<dim3(512), dim3(64), 0, stream>>>(
        inp, gk, rk, gb, w1, b1v, gam, bet, muv, vav, w2, bb2, Tp, flag, d_out);
    gru_sw_kernel<false><<<dim3(512), dim3(64), 0, stream>>>(
        inp, gk, rk, gb, w1, b1v, gam, bet, muv, vav, w2, bb2, Tp, flag, d_out);
}

// Round 5
// 508.497 us; speedup vs baseline: 1.6042x; 1.0905x over previous
//
#include <hip/hip_runtime.h>
#include <hip/hip_bf16.h>

// NewellGRUModel: B=512, S=1024, F=16, H=64.  bf16 in/out (proven r2..r15).
//
// r16: r12/r14/r15 all falsified the same assumption -- the compiler parks
// any >~100 long-lived VGPRs into AGPRs with per-use copy cost (r15:
// ~746 issue-cyc/step vs ~390 written instrs, VGPR=132). Fix: NO long-lived
// register arrays at all. Weights live in LDS, stored in the exact per-lane
// uint4/float4 order the loop consumes (lane-stride 16B -> sequential,
// conflict-free, aligned b128 reads):
//   wvs[block i][gate][lane] : uint4 of packed-f16 k-pairs 4i..4i+3  (24.5 KB)
//   xws[gate][j][lane]       : float4 of x-channels 4j..4j+3         (12 KB)
// Per step: 24 b128 (h-w) + 12 b128 (x-w) + 8 uniform b128 (h bcast) +
// 2 uniform (raw x). Register state: hr[8] + transients + biases < ~105.
// Iteration order keeps r15's boundary pipeline: [dots | gates | h write +
// hr reads | xw reads + x-proj(s+1)] -- the x-proj fills the h round-trip
// latency; in-order DS queue returns hr before the weight blocks.
// Arithmetic order bit-identical to r13 => absmax unchanged (9.77e-4).

typedef _Float16 f16x2 __attribute__((ext_vector_type(2)));
union H2U { unsigned int u; f16x2 h; };
union FU  { unsigned int u; float f; };

#if defined(__has_builtin)
#  if __has_builtin(__builtin_amdgcn_fdot2)
#    define HAS_FDOT2 1
#  endif
#endif
#ifndef HAS_FDOT2
#  define HAS_FDOT2 0
#endif

// acc += h2[0]*w2[0] + h2[1]*w2[1]  (fp32 accumulate)
static __device__ __forceinline__ float dot2acc(unsigned int hraw, unsigned int wraw, float acc) {
    H2U a, b; a.u = hraw; b.u = wraw;
#if HAS_FDOT2
    return __builtin_amdgcn_fdot2(a.h, b.h, acc, false);
#else
    return fmaf((float)a.h.x, (float)b.h.x, fmaf((float)a.h.y, (float)b.h.y, acc));
#endif
}

template<bool BF16>
struct IO {
    static __device__ __forceinline__ float ld(const void* p, int i) {
        if constexpr (BF16) {
            unsigned short u = ((const unsigned short*)p)[i];
            FU c; c.u = (unsigned int)u << 16;
            return c.f;
        } else {
            return ((const float*)p)[i];
        }
    }
    static __device__ __forceinline__ void st(void* p, int i, float v) {
        if constexpr (BF16) ((__hip_bfloat16*)p)[i] = __float2bfloat16(v);
        else ((float*)p)[i] = v;
    }
};

// mode: 0 = buffers are bf16, 1 = buffers are fp32.
__global__ void detect_dtype_kernel(const void* rkbuf, int* flag) {
    const float* f = (const float*)rkbuf;
    int ok = 0;
    for (int i = 0; i < 64; ++i) {
        float a = fabsf(f[i]);
        ok += (a > 1e-5f && a < 2.0f) ? 1 : 0;
    }
    *flag = (ok >= 48) ? 1 : 0;
}

template<bool BF16>
__global__ __launch_bounds__(64, 1)
void gru_ls_kernel(const void* __restrict__ inp, const void* __restrict__ gk,
                   const void* __restrict__ rk,  const void* __restrict__ gb,
                   const void* __restrict__ w1,  const void* __restrict__ b1v,
                   const void* __restrict__ gam, const void* __restrict__ bet,
                   const void* __restrict__ muv, const void* __restrict__ vav,
                   const void* __restrict__ w2,  const void* __restrict__ bb2,
                   const void* __restrict__ Tp,  const int* __restrict__ mode,
                   void* __restrict__ out)
{
    const int want = BF16 ? 0 : 1;
    if (*mode != want) return;   // uniform branch, whole block exits

    const int b = blockIdx.x;
    const int l = threadIdx.x;   // 0..63, lane = output unit

    // Raw x: BF16 -> whole batch (32 KB); FP32 -> half batch, restaged once.
    __shared__ __align__(16) unsigned char xsm[32768];
    __shared__ __align__(16) uint4  wvs[8*3*64];    // 24576 B  [i][g][l]
    __shared__ __align__(16) float4 xws[3*4*64];    // 12288 B  [g][j][l]
    __shared__ __align__(16) _Float16 hsf[64];
    __shared__ __align__(16) float sredf[64];

    using io = IO<BF16>;
    const uint4* gin = (const uint4*)inp;
    uint4* xvw = (uint4*)xsm;

    // ---- stage raw x (single wave: DS in-order, no barrier ever) ----
    if constexpr (BF16) {
#pragma unroll 4
        for (int i = 0; i < 32; ++i)
            xvw[i*64 + l] = gin[b*2048 + i*64 + l];     // whole batch, raw bf16
    } else {
#pragma unroll 4
        for (int i = 0; i < 32; ++i)
            xvw[i*64 + l] = gin[b*4096 + i*64 + l];     // first half, raw f32
    }

    // ---- stage h-weights: packed f16 pairs, consumption order ----
#pragma unroll 1
    for (int i = 0; i < 8; ++i) {
#pragma unroll
        for (int g = 0; g < 3; ++g) {
            unsigned int dw[4];
#pragma unroll
            for (int j = 0; j < 4; ++j) {
                const int p = 4*i + j;
                H2U u;
                u.h = f16x2{(_Float16)io::ld(rk, (2*p)*192 + g*64 + l),
                            (_Float16)io::ld(rk, (2*p+1)*192 + g*64 + l)};
                dw[j] = u.u;
            }
            wvs[(i*3 + g)*64 + l] = make_uint4(dw[0], dw[1], dw[2], dw[3]);
        }
    }
    // ---- stage x-proj weights, f32 (ch15 weight = 0 -> exact no-op) ----
#pragma unroll 1
    for (int g = 0; g < 3; ++g) {
#pragma unroll
        for (int j = 0; j < 4; ++j) {
            float v[4];
#pragma unroll
            for (int c4 = 0; c4 < 4; ++c4) {
                const int ch = 4*j + c4;
                v[c4] = (ch < 15) ? io::ld(gk, ch*192 + g*64 + l) : 0.0f;
            }
            xws[(g*4 + j)*64 + l] = make_float4(v[0], v[1], v[2], v[3]);
        }
    }

    const float bz  = io::ld(gb, l)      + io::ld(gb, 192 + l);
    const float br  = io::ld(gb, 64 + l) + io::ld(gb, 192 + 64 + l);
    const float bax = io::ld(gb, 128 + l);
    const float bah = io::ld(gb, 192 + 128 + l);   // b_r[h]

    // ---- delta-channel partial sum over staged portion ----
    float dsum = 0.0f;
    if constexpr (BF16) {
        const unsigned short* xs16 = (const unsigned short*)xsm;
#pragma unroll
        for (int k = 0; k < 16; ++k) {
            FU c; c.u = (unsigned int)xs16[(l + 64*k)*16 + 15] << 16;
            dsum += c.f;
        }
    } else {
        const float* xsf = (const float*)xsm;
#pragma unroll
        for (int k = 0; k < 8; ++k)
            dsum += xsf[(l + 64*k)*16 + 15];
    }

    // ---- per-lane stream pointers ----
    const uint4*  WVl = wvs + l;                  // WVl[(i*3+g)*64]
    const float4* XWl = xws + l;                  // XWl[(g*4+j)*64]
    const uint4*  hp  = (const uint4*)hsf;        // uniform -> broadcast
    const uint4*  xvr = (const uint4*)xsm;

    // carried raw-x regs for the NEXT step
    uint4  cr16[2] = {};
    float4 cr32[4] = {};

    // x-proj: consumes cr16/cr32, produces carried (azc, arc, axc).
    float azc, arc, axc;
    auto xproj = [&]() {
        float xc[16];
        if constexpr (BF16) {
            const unsigned int dw[8] = {cr16[0].x, cr16[0].y, cr16[0].z, cr16[0].w,
                                        cr16[1].x, cr16[1].y, cr16[1].z, cr16[1].w};
#pragma unroll
            for (int j2 = 0; j2 < 8; ++j2) {
                FU lo, hi; lo.u = dw[j2] << 16; hi.u = dw[j2] & 0xffff0000u;
                xc[2*j2] = lo.f; xc[2*j2+1] = hi.f;
            }
        } else {
            xc[0]=cr32[0].x; xc[1]=cr32[0].y; xc[2]=cr32[0].z; xc[3]=cr32[0].w;
            xc[4]=cr32[1].x; xc[5]=cr32[1].y; xc[6]=cr32[1].z; xc[7]=cr32[1].w;
            xc[8]=cr32[2].x; xc[9]=cr32[2].y; xc[10]=cr32[2].z; xc[11]=cr32[2].w;
            xc[12]=cr32[3].x; xc[13]=cr32[3].y; xc[14]=cr32[3].z; xc[15]=cr32[3].w;
        }
        const float4 qz0 = XWl[0],   qz1 = XWl[64],  qz2 = XWl[128], qz3 = XWl[192];
        const float4 qr0 = XWl[256], qr1 = XWl[320], qr2 = XWl[384], qr3 = XWl[448];
        const float4 qh0 = XWl[512], qh1 = XWl[576], qh2 = XWl[640], qh3 = XWl[704];
        float az = bz, ar_ = br, ax = bax;
        // channel-major, identical FP order to r13 (ch15 weight = 0: exact no-op)
        az=fmaf(xc[0],qz0.x,az);  ar_=fmaf(xc[0],qr0.x,ar_);  ax=fmaf(xc[0],qh0.x,ax);
        az=fmaf(xc[1],qz0.y,az);  ar_=fmaf(xc[1],qr0.y,ar_);  ax=fmaf(xc[1],qh0.y,ax);
        az=fmaf(xc[2],qz0.z,az);  ar_=fmaf(xc[2],qr0.z,ar_);  ax=fmaf(xc[2],qh0.z,ax);
        az=fmaf(xc[3],qz0.w,az);  ar_=fmaf(xc[3],qr0.w,ar_);  ax=fmaf(xc[3],qh0.w,ax);
        az=fmaf(xc[4],qz1.x,az);  ar_=fmaf(xc[4],qr1.x,ar_);  ax=fmaf(xc[4],qh1.x,ax);
        az=fmaf(xc[5],qz1.y,az);  ar_=fmaf(xc[5],qr1.y,ar_);  ax=fmaf(xc[5],qh1.y,ax);
        az=fmaf(xc[6],qz1.z,az);  ar_=fmaf(xc[6],qr1.z,ar_);  ax=fmaf(xc[6],qh1.z,ax);
        az=fmaf(xc[7],qz1.w,az);  ar_=fmaf(xc[7],qr1.w,ar_);  ax=fmaf(xc[7],qh1.w,ax);
        az=fmaf(xc[8],qz2.x,az);  ar_=fmaf(xc[8],qr2.x,ar_);  ax=fmaf(xc[8],qh2.x,ax);
        az=fmaf(xc[9],qz2.y,az);  ar_=fmaf(xc[9],qr2.y,ar_);  ax=fmaf(xc[9],qh2.y,ax);
        az=fmaf(xc[10],qz2.z,az); ar_=fmaf(xc[10],qr2.z,ar_); ax=fmaf(xc[10],qh2.z,ax);
        az=fmaf(xc[11],qz2.w,az); ar_=fmaf(xc[11],qr2.w,ar_); ax=fmaf(xc[11],qh2.w,ax);
        az=fmaf(xc[12],qz3.x,az); ar_=fmaf(xc[12],qr3.x,ar_); ax=fmaf(xc[12],qh3.x,ax);
        az=fmaf(xc[13],qz3.y,az); ar_=fmaf(xc[13],qr3.y,ar_); ax=fmaf(xc[13],qh3.y,ax);
        az=fmaf(xc[14],qz3.z,az); ar_=fmaf(xc[14],qr3.z,ar_); ax=fmaf(xc[14],qh3.z,ax);
        az=fmaf(xc[15],qz3.w,az); ar_=fmaf(xc[15],qr3.w,ar_); ax=fmaf(xc[15],qh3.w,ax);
        azc = az; arc = ar_; axc = ax;
    };

    // ---- prologue: x-proj for step 0 ----
    if constexpr (BF16) { cr16[0] = xvr[0]; cr16[1] = xvr[1]; }
    else { const float4* lp = (const float4*)xsm;
           cr32[0]=lp[0]; cr32[1]=lp[1]; cr32[2]=lp[2]; cr32[3]=lp[3]; }
    xproj();

    uint4 hr[8];
#pragma unroll
    for (int i = 0; i < 8; ++i) hr[i] = make_uint4(0, 0, 0, 0);
    float h = 0.0f;

    // ---- main loop: zero barriers, single wave ----
#pragma unroll 1
    for (int s = 0; s < 1024; ++s) {
        if constexpr (!BF16) {
            if (s == 511) {   // restage second half before reading x(512)
#pragma unroll 4
                for (int i = 0; i < 32; ++i)
                    xvw[i*64 + l] = gin[b*4096 + 2048 + i*64 + l];
                const float* xsf = (const float*)xsm;
#pragma unroll
                for (int k = 0; k < 8; ++k)
                    dsum += xsf[(l + 64*k)*16 + 15];
            }
        }
        // raw x for step s+1: uniform reads, land by iteration end
        if (s < 1023) {
            if constexpr (BF16) {
                cr16[0] = xvr[(s+1)*2]; cr16[1] = xvr[(s+1)*2 + 1];
            } else {
                const float4* lp = (const float4*)xsm;
                const int ix = ((s+1) & 511) * 4;
                cr32[0]=lp[ix]; cr32[1]=lp[ix+1]; cr32[2]=lp[ix+2]; cr32[3]=lp[ix+3];
            }
        }

        // ---- h-dots: stream weight blocks from LDS, 1-block lookahead ----
        float az = azc, ar_ = arc;
        const float ax = axc;
        float ah = bah;
        float az1 = 0.0f, ar1 = 0.0f, ah1 = 0.0f;
        uint4 cz = WVl[0], crr = WVl[64], chh = WVl[128];
#pragma unroll
        for (int i = 0; i < 8; ++i) {
            uint4 nz, nr, nh;
            if (i < 7) {
                nz = WVl[(i+1)*192];
                nr = WVl[(i+1)*192 + 64];
                nh = WVl[(i+1)*192 + 128];
            }
            const uint4 d = hr[i];
            if (i < 4) {
                az  = dot2acc(d.x, cz.x, az);  ar_ = dot2acc(d.x, crr.x, ar_); ah  = dot2acc(d.x, chh.x, ah);
                az  = dot2acc(d.y, cz.y, az);  ar_ = dot2acc(d.y, crr.y, ar_); ah  = dot2acc(d.y, chh.y, ah);
                az  = dot2acc(d.z, cz.z, az);  ar_ = dot2acc(d.z, crr.z, ar_); ah  = dot2acc(d.z, chh.z, ah);
                az  = dot2acc(d.w, cz.w, az);  ar_ = dot2acc(d.w, crr.w, ar_); ah  = dot2acc(d.w, chh.w, ah);
            } else {
                az1 = dot2acc(d.x, cz.x, az1); ar1 = dot2acc(d.x, crr.x, ar1); ah1 = dot2acc(d.x, chh.x, ah1);
                az1 = dot2acc(d.y, cz.y, az1); ar1 = dot2acc(d.y, crr.y, ar1); ah1 = dot2acc(d.y, chh.y, ah1);
                az1 = dot2acc(d.z, cz.z, az1); ar1 = dot2acc(d.z, crr.z, ar1); ah1 = dot2acc(d.z, chh.z, ah1);
                az1 = dot2acc(d.w, cz.w, az1); ar1 = dot2acc(d.w, crr.w, ar1); ah1 = dot2acc(d.w, chh.w, ah1);
            }
            cz = nz; crr = nr; chh = nh;
        }
        az += az1; ar_ += ar1; ah += ah1;

        const float z   = __builtin_amdgcn_rcpf(1.0f + __expf(-az));
        const float r   = __builtin_amdgcn_rcpf(1.0f + __expf(-ar_));
        const float pre = fmaf(r, ah, ax);
        const float e2  = __expf(2.0f * pre);
        const float th  = 1.0f - 2.0f * __builtin_amdgcn_rcpf(e2 + 1.0f);
        h = fmaf(z, h - th, th);     // z*h + (1-z)*tanh

        hsf[l] = (_Float16)h;        // same-wave DS: in-order
#pragma unroll
        for (int i = 0; i < 8; ++i) hr[i] = hp[i];   // issue h broadcast reads

        // x-proj for step s+1: xw reads queue BEHIND hr -> its FMA wait
        // covers the h round-trip latency.
        if (s < 1023) xproj();
    }

    // ---- epilogue: delta effect + dense head (single wave) ----
#pragma unroll
    for (int off = 1; off < 64; off <<= 1)
        dsum += __shfl_xor(dsum, off, 64);           // all lanes hold total
    const float T0 = io::ld(Tp, 0);
    const float state = fmaf(T0 * (1.0f / 1024.0f), dsum, h);
    sredf[l] = state;                                // same-wave DS, in-order

    const int j = l;   // 0..63
    float acc = io::ld(b1v, j);
#pragma unroll
    for (int k = 0; k < 64; ++k)
        acc = fmaf(sredf[k], io::ld(w1, k*64 + j), acc);
    acc = fmaxf(acc, 0.0f);                                  // ReLU
    const float inv = rsqrtf(io::ld(vav, j) + 0.001f);       // BN_EPS
    acc = fmaf((acc - io::ld(muv, j)) * inv, io::ld(gam, j), io::ld(bet, j));

    float v = acc * io::ld(w2, j);
#pragma unroll
    for (int off = 32; off > 0; off >>= 1)
        v += __shfl_down(v, off);
    if (j == 0) io::st(out, b, v + io::ld(bb2, 0));
}

extern "C" void kernel_launch(void* const* d_in, const int* in_sizes, int n_in,
                              void* d_out, int out_size, void* d_ws, size_t ws_size,
                              hipStream_t stream)
{
    const void* inp = d_in[0];   // (512,1024,16)
    const void* gk  = d_in[1];   // (15,192)
    const void* rk  = d_in[2];   // (64,192)
    const void* gb  = d_in[3];   // (2,192)
    const void* w1  = d_in[4];   // (64,64)
    const void* b1v = d_in[5];   // (64,)
    const void* gam = d_in[6];
    const void* bet = d_in[7];
    const void* muv = d_in[8];
    const void* vav = d_in[9];
    const void* w2  = d_in[10];  // (64,1)
    const void* bb2 = d_in[11];  // (1,)
    const void* Tp  = d_in[12];  // (1,)

    int* flag = (int*)d_ws;
    detect_dtype_kernel<<<dim3(1), dim3(1), 0, stream>>>(rk, flag);
    gru_ls_kernel<true ><<<dim3(512), dim3(64), 0, stream>>>(
        inp, gk, rk, gb, w1, b1v, gam, bet, muv, vav, w2, bb2, Tp, flag, d_out);
    gru_ls_kernel<false><<<dim3(512), dim3(64), 0, stream>>>(
        inp, gk, rk, gb, w1, b1v, gam, bet, muv, vav, w2, bb2, Tp, flag, d_out);
}